// Round 2
// baseline (238.506 us; speedup 1.0000x reference)
//
#include <hip/hip_runtime.h>

typedef __attribute__((ext_vector_type(8))) short short8;
typedef __attribute__((ext_vector_type(8))) unsigned short ushort8;
typedef __attribute__((ext_vector_type(4))) float f32x4;

static __device__ __forceinline__ unsigned short f2bf(float f) {
    union { float f; unsigned int u; } a; a.f = f;
    unsigned int u = a.u;
    return (unsigned short)((u + 0x7fffu + ((u >> 16) & 1u)) >> 16);  // RNE
}

// ---------------- prep (merged): modulated+demodulated weights (bf16) -------
// grid 8 (one block per batch), 256 thr. Phase 1: sumsq over all (rs,c) per f
// -> demod. Phase 2: transpose+scale+convert, wt[b][rs][f][c] c-contig.
__global__ void prep_all(const float* __restrict__ kern,
                         const float* __restrict__ style,
                         unsigned short* __restrict__ wt) {
    const int b = blockIdx.x;
    const int t = threadIdx.x;  // 256
    __shared__ float sty[128], dm[128], red[256];
    __shared__ float ts[32][132];
    if (t < 128) sty[t] = style[b * 128 + t] + 1.0f;
    __syncthreads();
    {   // sumsq: f = t&127, two c-halves per f
        const int f = t & 127, half = t >> 7;
        float s = 0.0f;
        for (int rs = 0; rs < 9; ++rs) {
            const float* kp = kern + (size_t)rs * 16384 + f;
            #pragma unroll 8
            for (int c = half * 64; c < half * 64 + 64; ++c) {
                float w = kp[(size_t)c * 128] * sty[c];
                s += w * w;
            }
        }
        red[t] = s;
    }
    __syncthreads();
    if (t < 128) dm[t] = rsqrtf(red[t] + red[t + 128] + 1e-8f);
    __syncthreads();
    for (int rs = 0; rs < 9; ++rs) {
        const float* kp = kern + (size_t)rs * 16384;
        unsigned short* wp = wt + ((size_t)b * 9 + rs) * 16384;
        for (int c0 = 0; c0 < 128; c0 += 32) {
            {
                const int fi = (t & 31) * 4;
                const int ci = t >> 5;
                #pragma unroll
                for (int k = 0; k < 4; ++k) {
                    const float4 v = *(const float4*)(kp + (size_t)(c0 + ci + 8 * k) * 128 + fi);
                    ts[ci + 8 * k][fi + 0] = v.x;
                    ts[ci + 8 * k][fi + 1] = v.y;
                    ts[ci + 8 * k][fi + 2] = v.z;
                    ts[ci + 8 * k][fi + 3] = v.w;
                }
            }
            __syncthreads();
            {
                const int cb = (t & 7) * 4;
                const int f2 = t >> 3;
                #pragma unroll
                for (int k = 0; k < 4; ++k) {
                    const int f = f2 + 32 * k;
                    ushort4 o;
                    o.x = f2bf(ts[cb + 0][f] * sty[c0 + cb + 0] * dm[f]);
                    o.y = f2bf(ts[cb + 1][f] * sty[c0 + cb + 1] * dm[f]);
                    o.z = f2bf(ts[cb + 2][f] * sty[c0 + cb + 2] * dm[f]);
                    o.w = f2bf(ts[cb + 3][f] * sty[c0 + cb + 3] * dm[f]);
                    *(ushort4*)(wp + (size_t)f * 128 + c0 + cb) = o;
                }
            }
            __syncthreads();
        }
    }
}

// ---------------- x -> padded bf16 NHWC [8][130][130][128] ----------------
#define PROW 16640      // 130*128
#define PPLANE 2163200  // 130*PROW
__global__ void cvt_x(const float* __restrict__ x, unsigned short* __restrict__ xbf) {
    const int id = blockIdx.x * 256 + threadIdx.x;  // one ushort8 chunk
    if (id >= 8 * 130 * 130 * 16) return;
    const int cg = id & 15;
    const int p  = id >> 4;
    const int wp = p % 130;
    const int q  = p / 130;
    const int hp = q % 130;
    const int b  = q / 130;
    ushort8 v = {0, 0, 0, 0, 0, 0, 0, 0};
    if (hp >= 1 && hp <= 128 && wp >= 1 && wp <= 128) {
        const float4* src = (const float4*)(x + (((size_t)b * 128 + (hp - 1)) * 128 + (wp - 1)) * 128 + cg * 8);
        float4 f0 = src[0];
        float4 f1 = src[1];
        v[0] = f2bf(f0.x); v[1] = f2bf(f0.y); v[2] = f2bf(f0.z); v[3] = f2bf(f0.w);
        v[4] = f2bf(f1.x); v[5] = f2bf(f1.y); v[6] = f2bf(f1.z); v[7] = f2bf(f1.w);
    }
    *(ushort8*)(xbf + (size_t)p * 128 + cg * 8) = v;
}

// ---------------- main conv v4: 512 thr (8 waves), grid 256 = 1 block/CU ----
// Wave tile: M=128 (one FULL output h-row, all w) x F=64 (fh half).
//  - B-LDS bytes/FLOP halved vs v2 (each B frag feeds 8 M-tiles).
//  - Per kc-step: 8 indep A-loads + 32 MFMAs => ILP hides global latency.
//  - Explicit A double-buffer: loads for step n+1 issue under step n's MFMAs.
// Regs: acc 128 + a0/a1 64 + bf 16 + addr ~20 = ~228 <= 256 (2 waves/SIMD).
// b = lin&7 keeps each batch on one XCD (L2 slice 4.3 MB + 294 KB wt).
__global__ __launch_bounds__(512, 2) void mdconv4(const unsigned short* __restrict__ xbf,
                                                  const unsigned short* __restrict__ wt,
                                                  float* __restrict__ out) {
    const int lin  = blockIdx.x;   // [0,256)
    const int b    = lin & 7;      // XCD-locality
    const int slot = lin >> 3;     // [0,32)
    const int fh   = slot & 1;
    const int hg   = slot >> 1;    // [0,16): 8 output h-rows per block
    const int tid  = threadIdx.x;

    __shared__ unsigned short wtl[9 * 64 * 128];  // 147,456 B

    {   // stage wt[b][rs][fh*64+f][:] -> wtl, XOR-swizzled rows
        for (int idx = tid; idx < 9216; idx += 512) {
            const int row = idx >> 4;        // rs*64 + f
            const int c8  = idx & 15;
            const int rs  = row >> 6;
            const int f   = row & 63;
            const ushort8 v = *(const ushort8*)(wt + (((size_t)b * 9 + rs) * 128 + fh * 64 + f) * 128 + c8 * 8);
            *(ushort8*)(wtl + row * 128 + ((c8 * 8) ^ ((row & 7) * 8))) = v;
        }
    }
    __syncthreads();  // the ONLY barrier

    const int lane = tid & 63;
    const int wv   = tid >> 6;       // [0,8): one h-row each
    const int fl   = lane & 15;
    const int quad = lane >> 4;
    const int kq   = quad * 8;
    const int xh   = (fl & 7) * 8;   // B swizzle XOR (ushort units)

    const int hrow = hg * 8 + wv;    // output h, [0,128)

    f32x4 acc[8][4];
    #pragma unroll
    for (int mt = 0; mt < 8; ++mt)
        #pragma unroll
        for (int ft = 0; ft < 4; ++ft)
            acc[mt][ft] = (f32x4){0.f, 0.f, 0.f, 0.f};

    const unsigned short* xb = xbf + (size_t)b * PPLANE;

    // step st in [0,36): rs = st>>2 (tap), kc = st&3 (k-chunk of 32)
#define LOADA(buf, st) {                                                          \
    const int rs_ = (st) >> 2, kc_ = (st) & 3;                                    \
    const int r_ = rs_ / 3, s_ = rs_ % 3;                                         \
    const unsigned short* ap =                                                    \
        xb + ((size_t)(hrow + r_) * 130 + s_ + fl) * 128 + kq + kc_ * 32;         \
    _Pragma("unroll")                                                             \
    for (int mt = 0; mt < 8; ++mt) buf[mt] = *(const short8*)(ap + mt * 2048);    \
}

#define COMPUTE(buf, st) {                                                        \
    const int rs_ = (st) >> 2, kc_ = (st) & 3;                                    \
    const unsigned short* bp = wtl + rs_ * 8192 + fl * 128 + ((kc_ * 32 + kq) ^ xh); \
    short8 bfv[4];                                                                \
    _Pragma("unroll")                                                             \
    for (int ft = 0; ft < 4; ++ft) bfv[ft] = *(const short8*)(bp + ft * 2048);    \
    _Pragma("unroll")                                                             \
    for (int mt = 0; mt < 8; ++mt)                                                \
        _Pragma("unroll")                                                         \
        for (int ft = 0; ft < 4; ++ft)                                            \
            acc[mt][ft] =                                                         \
                __builtin_amdgcn_mfma_f32_16x16x32_bf16(buf[mt], bfv[ft], acc[mt][ft], 0, 0, 0); \
}

    short8 a0[8], a1[8];
    LOADA(a0, 0);
    #pragma unroll
    for (int st = 0; st < 36; st += 2) {
        LOADA(a1, st + 1);
        COMPUTE(a0, st);
        if (st + 2 < 36) LOADA(a0, st + 2);
        COMPUTE(a1, st + 1);
    }
#undef LOADA
#undef COMPUTE

    // D: col=lane&15 -> f-within-tile, row=quad*4+reg -> w-within-Mtile.
    // Store order mt,reg,ft: the 4 ft-stores per w are adjacent 64B segments
    // (f contiguous across lanes) -> coalesce into 256B per w.
    float* ob = out + ((size_t)(b * 128 + hrow) * 128) * 128 + fh * 64;
    #pragma unroll
    for (int mt = 0; mt < 8; ++mt) {
        #pragma unroll
        for (int reg = 0; reg < 4; ++reg) {
            const int w = mt * 16 + quad * 4 + reg;
            #pragma unroll
            for (int ft = 0; ft < 4; ++ft)
                ob[(size_t)w * 128 + ft * 16 + fl] = acc[mt][ft][reg];
        }
    }
}

// ---------------- R2 fallback (used only if ws too small) ----------------
__global__ void mdconv_fb(const float* __restrict__ x,
                          const unsigned short* __restrict__ wt,
                          float* __restrict__ out) {
    const int lin = blockIdx.x;
    const int b   = lin & 7;
    const int sp  = lin >> 3;
    const int h0  = (sp >> 3) * 8;
    const int w0  = (sp & 7) * 16;
    const int tid = threadIdx.x;
    __shared__ unsigned short xs[180 * 138];
    {
        const float* xb = x + (size_t)b * (128 * 128 * 128);
        for (int id = tid; id < 180 * 16; id += 256) {
            int p  = id >> 4;
            int cg = id & 15;
            int pr = p / 18;
            int pc = p - pr * 18;
            int hh = h0 - 1 + pr;
            int ww = w0 - 1 + pc;
            ushort8 v = {0, 0, 0, 0, 0, 0, 0, 0};
            if ((unsigned)hh < 128u && (unsigned)ww < 128u) {
                const float4* src = (const float4*)(xb + ((size_t)(hh * 128 + ww) * 128 + cg * 8));
                float4 f0 = src[0];
                float4 f1 = src[1];
                v[0] = f2bf(f0.x); v[1] = f2bf(f0.y); v[2] = f2bf(f0.z); v[3] = f2bf(f0.w);
                v[4] = f2bf(f1.x); v[5] = f2bf(f1.y); v[6] = f2bf(f1.z); v[7] = f2bf(f1.w);
            }
            *(ushort8*)(xs + p * 138 + cg * 8) = v;
        }
    }
    __syncthreads();
    const int lane = tid & 63;
    const int wave = tid >> 6;
    const int fl   = lane & 15;
    const int quad = lane >> 4;
    const int kq   = quad * 8;
    f32x4 acc[8][2];
    #pragma unroll
    for (int mt = 0; mt < 8; ++mt)
        #pragma unroll
        for (int j = 0; j < 2; ++j)
            acc[mt][j] = (f32x4){0.f, 0.f, 0.f, 0.f};
    const unsigned short* wtb = wt + (size_t)b * (9 * 128 * 128) + (size_t)wave * 4096 + fl * 128 + kq;
    #pragma unroll
    for (int rs = 0; rs < 9; ++rs) {
        const int r = rs / 3, s = rs % 3;
        #pragma unroll
        for (int kc = 0; kc < 4; ++kc) {
            const int k0 = kc * 32 + kq;
            short8 a[8];
            #pragma unroll
            for (int mt = 0; mt < 8; ++mt)
                a[mt] = *(const short8*)(xs + ((mt + r) * 18 + fl + s) * 138 + k0);
            #pragma unroll
            for (int j = 0; j < 2; ++j) {
                short8 bf = *(const short8*)(wtb + rs * 16384 + j * 2048 + kc * 32);
                #pragma unroll
                for (int mt = 0; mt < 8; ++mt)
                    acc[mt][j] = __builtin_amdgcn_mfma_f32_16x16x32_bf16(a[mt], bf, acc[mt][j], 0, 0, 0);
            }
        }
    }
    float* ob = out + ((size_t)(b * 128 + h0) * 128 + w0) * 128;
    #pragma unroll
    for (int mt = 0; mt < 8; ++mt)
        #pragma unroll
        for (int j = 0; j < 2; ++j) {
            const int f = (wave * 2 + j) * 16 + fl;
            #pragma unroll
            for (int reg = 0; reg < 4; ++reg)
                ob[((size_t)(mt * 128 + quad * 4 + reg)) * 128 + f] = acc[mt][j][reg];
        }
}

extern "C" void kernel_launch(void* const* d_in, const int* in_sizes, int n_in,
                              void* d_out, int out_size, void* d_ws, size_t ws_size,
                              hipStream_t stream) {
    const float* x     = (const float*)d_in[0];
    const float* style = (const float*)d_in[1];
    const float* kern  = (const float*)d_in[2];
    float* out = (float*)d_out;

    const size_t XBF_BYTES = (size_t)8 * 130 * 130 * 128 * 2;  // 34,611,200
    const size_t WT_BYTES  = (size_t)8 * 9 * 128 * 128 * 2;    //  2,359,296
    const size_t NEED      = XBF_BYTES + WT_BYTES;

    if (ws_size >= NEED) {
        unsigned short* xbf = (unsigned short*)d_ws;
        unsigned short* wt  = (unsigned short*)((char*)d_ws + XBF_BYTES);
        prep_all<<<dim3(8), dim3(256), 0, stream>>>(kern, style, wt);
        cvt_x<<<dim3((8 * 130 * 130 * 16 + 255) / 256), dim3(256), 0, stream>>>(x, xbf);
        mdconv4<<<dim3(256), dim3(512), 0, stream>>>(xbf, wt, out);
    } else {
        unsigned short* wt = (unsigned short*)d_ws;
        prep_all<<<dim3(8), dim3(256), 0, stream>>>(kern, style, wt);
        mdconv_fb<<<dim3(1024), dim3(256), 0, stream>>>(x, wt, out);
    }
}

// Round 4
// 194.945 us; speedup vs baseline: 1.2235x; 1.2235x over previous
//
#include <hip/hip_runtime.h>

typedef __attribute__((ext_vector_type(8))) short short8;
typedef __attribute__((ext_vector_type(8))) unsigned short ushort8;
typedef __attribute__((ext_vector_type(4))) float f32x4;

static __device__ __forceinline__ unsigned short f2bf(float f) {
    union { float f; unsigned int u; } a; a.f = f;
    unsigned int u = a.u;
    return (unsigned short)((u + 0x7fffu + ((u >> 16) & 1u)) >> 16);  // RNE
}

// ---------------- prep: modulated+demodulated weights (bf16) ----------------
// Stage 1: partial[b][rs][f] = sum_c (kern[rs][c][f] * (style[b][c]+1))^2
__global__ void prep_sumsq(const float* __restrict__ kern,
                           const float* __restrict__ style,
                           float* __restrict__ partial) {
    const int rs = blockIdx.x;   // 0..8
    const int b  = blockIdx.y;   // 0..7
    const int t  = threadIdx.x;  // 256
    __shared__ float sty[128];
    __shared__ float red[256];
    if (t < 128) sty[t] = style[b * 128 + t] + 1.0f;
    __syncthreads();
    const int f = t & 127, half = t >> 7;
    const float* kp = kern + (size_t)rs * 16384 + f;
    float s = 0.0f;
    #pragma unroll 8
    for (int c = half * 64; c < half * 64 + 64; ++c) {
        float w = kp[(size_t)c * 128] * sty[c];
        s += w * w;
    }
    red[t] = s;
    __syncthreads();
    if (t < 128) partial[((size_t)b * 9 + rs) * 128 + t] = red[t] + red[t + 128];
}

// Stage 2: wt[b][rs][f][c] = bf16(kern[rs][c][f] * sty[c] * demod[f]), c-contig.
__global__ void prep_wt(const float* __restrict__ kern,
                        const float* __restrict__ style,
                        const float* __restrict__ partial,
                        unsigned short* __restrict__ wt) {
    const int rs = blockIdx.x, b = blockIdx.y;
    const int t  = threadIdx.x;  // 256
    __shared__ float sty[128], dm[128];
    __shared__ float ts[32][132];
    if (t < 128) {
        sty[t] = style[b * 128 + t] + 1.0f;
    } else {
        const int f = t - 128;
        float s = 0.0f;
        #pragma unroll
        for (int r = 0; r < 9; ++r) s += partial[((size_t)b * 9 + r) * 128 + f];
        dm[f] = rsqrtf(s + 1e-8f);
    }
    __syncthreads();
    const float* kp = kern + (size_t)rs * 16384;
    unsigned short* wp = wt + ((size_t)b * 9 + rs) * 16384;
    for (int c0 = 0; c0 < 128; c0 += 32) {
        {
            const int fi = (t & 31) * 4;
            const int ci = t >> 5;
            #pragma unroll
            for (int k = 0; k < 4; ++k) {
                const float4 v = *(const float4*)(kp + (size_t)(c0 + ci + 8 * k) * 128 + fi);
                ts[ci + 8 * k][fi + 0] = v.x;
                ts[ci + 8 * k][fi + 1] = v.y;
                ts[ci + 8 * k][fi + 2] = v.z;
                ts[ci + 8 * k][fi + 3] = v.w;
            }
        }
        __syncthreads();
        {
            const int cb = (t & 7) * 4;
            const int f2 = t >> 3;
            #pragma unroll
            for (int k = 0; k < 4; ++k) {
                const int f = f2 + 32 * k;
                ushort4 o;
                o.x = f2bf(ts[cb + 0][f] * sty[c0 + cb + 0] * dm[f]);
                o.y = f2bf(ts[cb + 1][f] * sty[c0 + cb + 1] * dm[f]);
                o.z = f2bf(ts[cb + 2][f] * sty[c0 + cb + 2] * dm[f]);
                o.w = f2bf(ts[cb + 3][f] * sty[c0 + cb + 3] * dm[f]);
                *(ushort4*)(wp + (size_t)f * 128 + c0 + cb) = o;
            }
        }
        __syncthreads();
    }
}

// ---------------- x -> padded bf16 NHWC [8][130][130][128] ----------------
#define PROW 16640      // 130*128
#define PPLANE 2163200  // 130*PROW
__global__ void cvt_x(const float* __restrict__ x, unsigned short* __restrict__ xbf) {
    const int id = blockIdx.x * 256 + threadIdx.x;  // one ushort8 chunk
    if (id >= 8 * 130 * 130 * 16) return;
    const int cg = id & 15;
    const int p  = id >> 4;
    const int wp = p % 130;
    const int q  = p / 130;
    const int hp = q % 130;
    const int b  = q / 130;
    ushort8 v = {0, 0, 0, 0, 0, 0, 0, 0};
    if (hp >= 1 && hp <= 128 && wp >= 1 && wp <= 128) {
        const float4* src = (const float4*)(x + (((size_t)b * 128 + (hp - 1)) * 128 + (wp - 1)) * 128 + cg * 8);
        float4 f0 = src[0];
        float4 f1 = src[1];
        v[0] = f2bf(f0.x); v[1] = f2bf(f0.y); v[2] = f2bf(f0.z); v[3] = f2bf(f0.w);
        v[4] = f2bf(f1.x); v[5] = f2bf(f1.y); v[6] = f2bf(f1.z); v[7] = f2bf(f1.w);
    }
    *(ushort8*)(xbf + (size_t)p * 128 + cg * 8) = v;
}

// ---------------- main conv v5: v4 + sched_barrier-pinned pipeline ----------
// 512 thr (8 waves), grid 256 = 1 block/CU. Wave tile M=128 (full h-row) x F=64.
// Phase structure per half-step, pinned with sched_barrier(0):
//   { issue 8 global A-loads for st+1 ; issue 4 ds_reads B for st }  | fence
//   { 32 MFMAs for st (vmcnt counted by compiler, lands AFTER issue) } | fence
// This stops the register allocator from sinking the A-prefetch into the MFMA
// cluster (live-range shortening), which collapses the double buffer.
__global__ __launch_bounds__(512, 2) void mdconv5(const unsigned short* __restrict__ xbf,
                                                  const unsigned short* __restrict__ wt,
                                                  float* __restrict__ out) {
    const int lin  = blockIdx.x;   // [0,256)
    const int b    = lin & 7;      // XCD-locality: batch == XCD
    const int slot = lin >> 3;     // [0,32)
    const int fh   = slot & 1;
    const int hg   = slot >> 1;    // [0,16): 8 output h-rows per block
    const int tid  = threadIdx.x;

    __shared__ unsigned short wtl[9 * 64 * 128];  // 147,456 B

    {   // stage wt[b][rs][fh*64+f][:] -> wtl, XOR-swizzled rows
        for (int idx = tid; idx < 9216; idx += 512) {
            const int row = idx >> 4;        // rs*64 + f
            const int c8  = idx & 15;
            const int rs  = row >> 6;
            const int f   = row & 63;
            const ushort8 v = *(const ushort8*)(wt + (((size_t)b * 9 + rs) * 128 + fh * 64 + f) * 128 + c8 * 8);
            *(ushort8*)(wtl + row * 128 + ((c8 * 8) ^ ((row & 7) * 8))) = v;
        }
    }
    __syncthreads();  // the ONLY barrier

    const int lane = tid & 63;
    const int wv   = tid >> 6;       // [0,8): one h-row each
    const int fl   = lane & 15;
    const int quad = lane >> 4;
    const int kq   = quad * 8;
    const int xh   = (fl & 7) * 8;   // B swizzle XOR (ushort units)

    const int hrow = hg * 8 + wv;    // output h, [0,128)

    f32x4 acc[8][4];
    #pragma unroll
    for (int mt = 0; mt < 8; ++mt)
        #pragma unroll
        for (int ft = 0; ft < 4; ++ft)
            acc[mt][ft] = (f32x4){0.f, 0.f, 0.f, 0.f};

    const unsigned short* xb = xbf + (size_t)b * PPLANE;

    // step st in [0,36): rs = st>>2 (tap), kc = st&3 (k-chunk of 32)
#define LOADA(buf, st) {                                                          \
    const int rs_ = (st) >> 2, kc_ = (st) & 3;                                    \
    const int r_ = rs_ / 3, s_ = rs_ % 3;                                         \
    const unsigned short* ap =                                                    \
        xb + ((size_t)(hrow + r_) * 130 + s_ + fl) * 128 + kq + kc_ * 32;         \
    _Pragma("unroll")                                                             \
    for (int mt = 0; mt < 8; ++mt) buf[mt] = *(const short8*)(ap + mt * 2048);    \
}

#define LOADB(st) {                                                               \
    const int rs_ = (st) >> 2, kc_ = (st) & 3;                                    \
    const unsigned short* bp = wtl + rs_ * 8192 + fl * 128 + ((kc_ * 32 + kq) ^ xh); \
    _Pragma("unroll")                                                             \
    for (int ft = 0; ft < 4; ++ft) bfv[ft] = *(const short8*)(bp + ft * 2048);    \
}

#define MFMAS(buf) {                                                              \
    _Pragma("unroll")                                                             \
    for (int mt = 0; mt < 8; ++mt)                                                \
        _Pragma("unroll")                                                         \
        for (int ft = 0; ft < 4; ++ft)                                            \
            acc[mt][ft] =                                                         \
                __builtin_amdgcn_mfma_f32_16x16x32_bf16(buf[mt], bfv[ft], acc[mt][ft], 0, 0, 0); \
}

    short8 a0[8], a1[8], bfv[4];
    LOADA(a0, 0);
    #pragma unroll
    for (int st = 0; st < 36; st += 2) {
        LOADA(a1, st + 1);          // prefetch A for st+1
        LOADB(st);                  // B frags for st
        __builtin_amdgcn_sched_barrier(0);
        MFMAS(a0);                  // compute st (compiler's vmcnt is counted)
        __builtin_amdgcn_sched_barrier(0);
        if (st + 2 < 36) LOADA(a0, st + 2);
        LOADB(st + 1);
        __builtin_amdgcn_sched_barrier(0);
        MFMAS(a1);                  // compute st+1
        __builtin_amdgcn_sched_barrier(0);
    }
#undef LOADA
#undef LOADB
#undef MFMAS

    // D: col=lane&15 -> f-within-tile, row=quad*4+reg -> w-within-Mtile.
    float* ob = out + ((size_t)(b * 128 + hrow) * 128) * 128 + fh * 64;
    #pragma unroll
    for (int mt = 0; mt < 8; ++mt) {
        #pragma unroll
        for (int reg = 0; reg < 4; ++reg) {
            const int w = mt * 16 + quad * 4 + reg;
            #pragma unroll
            for (int ft = 0; ft < 4; ++ft)
                ob[(size_t)w * 128 + ft * 16 + fl] = acc[mt][ft][reg];
        }
    }
}

// ---------------- R2 fallback (used only if ws too small) ----------------
__global__ void mdconv_fb(const float* __restrict__ x,
                          const unsigned short* __restrict__ wt,
                          float* __restrict__ out) {
    const int lin = blockIdx.x;
    const int b   = lin & 7;
    const int sp  = lin >> 3;
    const int h0  = (sp >> 3) * 8;
    const int w0  = (sp & 7) * 16;
    const int tid = threadIdx.x;
    __shared__ unsigned short xs[180 * 138];
    {
        const float* xb = x + (size_t)b * (128 * 128 * 128);
        for (int id = tid; id < 180 * 16; id += 256) {
            int p  = id >> 4;
            int cg = id & 15;
            int pr = p / 18;
            int pc = p - pr * 18;
            int hh = h0 - 1 + pr;
            int ww = w0 - 1 + pc;
            ushort8 v = {0, 0, 0, 0, 0, 0, 0, 0};
            if ((unsigned)hh < 128u && (unsigned)ww < 128u) {
                const float4* src = (const float4*)(xb + ((size_t)(hh * 128 + ww) * 128 + cg * 8));
                float4 f0 = src[0];
                float4 f1 = src[1];
                v[0] = f2bf(f0.x); v[1] = f2bf(f0.y); v[2] = f2bf(f0.z); v[3] = f2bf(f0.w);
                v[4] = f2bf(f1.x); v[5] = f2bf(f1.y); v[6] = f2bf(f1.z); v[7] = f2bf(f1.w);
            }
            *(ushort8*)(xs + p * 138 + cg * 8) = v;
        }
    }
    __syncthreads();
    const int lane = tid & 63;
    const int wave = tid >> 6;
    const int fl   = lane & 15;
    const int quad = lane >> 4;
    const int kq   = quad * 8;
    f32x4 acc[8][2];
    #pragma unroll
    for (int mt = 0; mt < 8; ++mt)
        #pragma unroll
        for (int j = 0; j < 2; ++j)
            acc[mt][j] = (f32x4){0.f, 0.f, 0.f, 0.f};
    const unsigned short* wtb = wt + (size_t)b * (9 * 128 * 128) + (size_t)wave * 4096 + fl * 128 + kq;
    #pragma unroll
    for (int rs = 0; rs < 9; ++rs) {
        const int r = rs / 3, s = rs % 3;
        #pragma unroll
        for (int kc = 0; kc < 4; ++kc) {
            const int k0 = kc * 32 + kq;
            short8 a[8];
            #pragma unroll
            for (int mt = 0; mt < 8; ++mt)
                a[mt] = *(const short8*)(xs + ((mt + r) * 18 + fl + s) * 138 + k0);
            #pragma unroll
            for (int j = 0; j < 2; ++j) {
                short8 bf = *(const short8*)(wtb + rs * 16384 + j * 2048 + kc * 32);
                #pragma unroll
                for (int mt = 0; mt < 8; ++mt)
                    acc[mt][j] = __builtin_amdgcn_mfma_f32_16x16x32_bf16(a[mt], bf, acc[mt][j], 0, 0, 0);
            }
        }
    }
    float* ob = out + ((size_t)(b * 128 + h0) * 128 + w0) * 128;
    #pragma unroll
    for (int mt = 0; mt < 8; ++mt)
        #pragma unroll
        for (int j = 0; j < 2; ++j) {
            const int f = (wave * 2 + j) * 16 + fl;
            #pragma unroll
            for (int reg = 0; reg < 4; ++reg)
                ob[((size_t)(mt * 128 + quad * 4 + reg)) * 128 + f] = acc[mt][j][reg];
        }
}

extern "C" void kernel_launch(void* const* d_in, const int* in_sizes, int n_in,
                              void* d_out, int out_size, void* d_ws, size_t ws_size,
                              hipStream_t stream) {
    const float* x     = (const float*)d_in[0];
    const float* style = (const float*)d_in[1];
    const float* kern  = (const float*)d_in[2];
    float* out = (float*)d_out;

    const size_t XBF_BYTES = (size_t)8 * 130 * 130 * 128 * 2;  // 34,611,200
    const size_t WT_BYTES  = (size_t)8 * 9 * 128 * 128 * 2;    //  2,359,296
    const size_t NEED      = XBF_BYTES + WT_BYTES + 36864;

    if (ws_size >= NEED) {
        unsigned short* xbf = (unsigned short*)d_ws;
        unsigned short* wt  = (unsigned short*)((char*)d_ws + XBF_BYTES);
        float* partial      = (float*)((char*)d_ws + XBF_BYTES + WT_BYTES);
        prep_sumsq<<<dim3(9, 8), dim3(256), 0, stream>>>(kern, style, partial);
        prep_wt<<<dim3(9, 8), dim3(256), 0, stream>>>(kern, style, partial, wt);
        cvt_x<<<dim3((8 * 130 * 130 * 16 + 255) / 256), dim3(256), 0, stream>>>(x, xbf);
        mdconv5<<<dim3(256), dim3(512), 0, stream>>>(xbf, wt, out);
    } else {
        unsigned short* wt = (unsigned short*)d_ws;
        float* partial     = (float*)((char*)d_ws + WT_BYTES);
        prep_sumsq<<<dim3(9, 8), dim3(256), 0, stream>>>(kern, style, partial);
        prep_wt<<<dim3(9, 8), dim3(256), 0, stream>>>(kern, style, partial, wt);
        mdconv_fb<<<dim3(1024), dim3(256), 0, stream>>>(x, wt, out);
    }
}

// Round 5
// 165.560 us; speedup vs baseline: 1.4406x; 1.1775x over previous
//
#include <hip/hip_runtime.h>

typedef __attribute__((ext_vector_type(8))) short short8;
typedef __attribute__((ext_vector_type(8))) unsigned short ushort8;
typedef __attribute__((ext_vector_type(4))) float f32x4;

static __device__ __forceinline__ unsigned short f2bf(float f) {
    union { float f; unsigned int u; } a; a.f = f;
    unsigned int u = a.u;
    return (unsigned short)((u + 0x7fffu + ((u >> 16) & 1u)) >> 16);  // RNE
}

// async global->LDS, 16B per lane. LDS dest is wave-uniform base + lane*16;
// we pass each lane's own pointer, which coincides with that rule because
// lane l's chunk sits exactly at base+l*16 (verified mapping below).
static __device__ __forceinline__ void gll16(const unsigned short* g, unsigned short* l) {
    __builtin_amdgcn_global_load_lds(
        (const __attribute__((address_space(1))) unsigned int*)g,
        (__attribute__((address_space(3))) unsigned int*)l, 16, 0, 0);
}

// ---------------- prep: modulated+demodulated weights (bf16) ----------------
// Stage 1: partial[b][rs][f] = sum_c (kern[rs][c][f] * (style[b][c]+1))^2
__global__ void prep_sumsq(const float* __restrict__ kern,
                           const float* __restrict__ style,
                           float* __restrict__ partial) {
    const int rs = blockIdx.x;   // 0..8
    const int b  = blockIdx.y;   // 0..7
    const int t  = threadIdx.x;  // 256
    __shared__ float sty[128];
    __shared__ float red[256];
    if (t < 128) sty[t] = style[b * 128 + t] + 1.0f;
    __syncthreads();
    const int f = t & 127, half = t >> 7;
    const float* kp = kern + (size_t)rs * 16384 + f;
    float s = 0.0f;
    #pragma unroll 8
    for (int c = half * 64; c < half * 64 + 64; ++c) {
        float w = kp[(size_t)c * 128] * sty[c];
        s += w * w;
    }
    red[t] = s;
    __syncthreads();
    if (t < 128) partial[((size_t)b * 9 + rs) * 128 + t] = red[t] + red[t + 128];
}

// Stage 2: wt[b][rs][f][c] = bf16(kern[rs][c][f] * sty[c] * demod[f]), c-contig.
__global__ void prep_wt(const float* __restrict__ kern,
                        const float* __restrict__ style,
                        const float* __restrict__ partial,
                        unsigned short* __restrict__ wt) {
    const int rs = blockIdx.x, b = blockIdx.y;
    const int t  = threadIdx.x;  // 256
    __shared__ float sty[128], dm[128];
    __shared__ float ts[32][132];
    if (t < 128) {
        sty[t] = style[b * 128 + t] + 1.0f;
    } else {
        const int f = t - 128;
        float s = 0.0f;
        #pragma unroll
        for (int r = 0; r < 9; ++r) s += partial[((size_t)b * 9 + r) * 128 + f];
        dm[f] = rsqrtf(s + 1e-8f);
    }
    __syncthreads();
    const float* kp = kern + (size_t)rs * 16384;
    unsigned short* wp = wt + ((size_t)b * 9 + rs) * 16384;
    for (int c0 = 0; c0 < 128; c0 += 32) {
        {
            const int fi = (t & 31) * 4;
            const int ci = t >> 5;
            #pragma unroll
            for (int k = 0; k < 4; ++k) {
                const float4 v = *(const float4*)(kp + (size_t)(c0 + ci + 8 * k) * 128 + fi);
                ts[ci + 8 * k][fi + 0] = v.x;
                ts[ci + 8 * k][fi + 1] = v.y;
                ts[ci + 8 * k][fi + 2] = v.z;
                ts[ci + 8 * k][fi + 3] = v.w;
            }
        }
        __syncthreads();
        {
            const int cb = (t & 7) * 4;
            const int f2 = t >> 3;
            #pragma unroll
            for (int k = 0; k < 4; ++k) {
                const int f = f2 + 32 * k;
                ushort4 o;
                o.x = f2bf(ts[cb + 0][f] * sty[c0 + cb + 0] * dm[f]);
                o.y = f2bf(ts[cb + 1][f] * sty[c0 + cb + 1] * dm[f]);
                o.z = f2bf(ts[cb + 2][f] * sty[c0 + cb + 2] * dm[f]);
                o.w = f2bf(ts[cb + 3][f] * sty[c0 + cb + 3] * dm[f]);
                *(ushort4*)(wp + (size_t)f * 128 + c0 + cb) = o;
            }
        }
        __syncthreads();
    }
}

// ---------------- x -> padded bf16 NHWC [8][130][130][128] ----------------
#define PROW 16640      // 130*128
#define PPLANE 2163200  // 130*PROW
__global__ void cvt_x(const float* __restrict__ x, unsigned short* __restrict__ xbf) {
    const int id = blockIdx.x * 256 + threadIdx.x;  // one ushort8 chunk
    if (id >= 8 * 130 * 130 * 16) return;
    const int cg = id & 15;
    const int p  = id >> 4;
    const int wp = p % 130;
    const int q  = p / 130;
    const int hp = q % 130;
    const int b  = q / 130;
    ushort8 v = {0, 0, 0, 0, 0, 0, 0, 0};
    if (hp >= 1 && hp <= 128 && wp >= 1 && wp <= 128) {
        const float4* src = (const float4*)(x + (((size_t)b * 128 + (hp - 1)) * 128 + (wp - 1)) * 128 + cg * 8);
        float4 f0 = src[0];
        float4 f1 = src[1];
        v[0] = f2bf(f0.x); v[1] = f2bf(f0.y); v[2] = f2bf(f0.z); v[3] = f2bf(f0.w);
        v[4] = f2bf(f1.x); v[5] = f2bf(f1.y); v[6] = f2bf(f1.z); v[7] = f2bf(f1.w);
    }
    *(ushort8*)(xbf + (size_t)p * 128 + cg * 8) = v;
}

// ---------------- main conv v6: m97-style dbuf LDS implicit GEMM ----------
// 1024 blocks (b = lin&7 -> XCD, h = lin>>3), 256 thr = 4 waves.
// Block tile: one h-row, 128w x 128f. Wave (2x2): 64w x 64f, acc[4][4]=64.
// K = 36 steps (9 taps x 4 c-chunks of 32). Per step: stage next A(8KB)+B(8KB)
// via global_load_lds(16B) into buf^1, ds_read frags from buf, 16 MFMAs,
// __syncthreads (drains vmcnt+lgkm = the m97 pipeline boundary).
// LDS 32KB -> 4 blocks/CU; launch_bounds(256,4) -> 16 waves/CU (4/SIMD).
// LDS maps: Abuf[w][32c] el=w*32+c', chunk j=(w=j>>2, q=j&3) at el 8j. Thread t
// stages chunks t and t+256 => lane l's dest = wavebase + l*16B exactly.
__global__ __launch_bounds__(256, 4) void mdconv6(const unsigned short* __restrict__ xbf,
                                                  const unsigned short* __restrict__ wt,
                                                  float* __restrict__ out) {
    const int lin = blockIdx.x;   // [0,1024)
    const int b   = lin & 7;      // XCD-locality: batch == XCD
    const int h   = lin >> 3;     // output h-row [0,128)
    const int tid = threadIdx.x;

    __shared__ unsigned short lsh[2 * 8192];  // 32,768 B: [buf][A 4096 | B 4096] els

    const unsigned short* xb  = xbf + (size_t)b * PPLANE;
    const unsigned short* wtb = wt + (size_t)b * 9 * 16384;

    // staging offsets (element units). chunk j: w=j>>2, q=j&3 -> src w*128 + q*8.
    const int a0off = (tid >> 2) * 128 + (tid & 3) * 8;  // chunk t ; chunk t+256 = +8192

    const int lane = tid & 63;
    const int wv   = tid >> 6;       // 2x2 waves
    const int fl   = lane & 15;
    const int quad = lane >> 4;
    const int wrb  = (wv >> 1) * 64; // w base
    const int fcb  = (wv & 1) * 64;  // f base
    const int ab_rd = (wrb + fl) * 32 + quad * 8;         // + cur*8192 + mt*512
    const int bb_rd = 4096 + (fcb + fl) * 32 + quad * 8;  // + cur*8192 + ft*512

    f32x4 acc[4][4];
    #pragma unroll
    for (int mt = 0; mt < 4; ++mt)
        #pragma unroll
        for (int ft = 0; ft < 4; ++ft)
            acc[mt][ft] = (f32x4){0.f, 0.f, 0.f, 0.f};

    // step st: rs = st>>2 (tap), kc = st&3 (c-chunk)
#define STAGE(st, nxt) {                                                          \
    const int rs_ = (st) >> 2, kc_ = (st) & 3;                                    \
    const int r_ = rs_ / 3, s_ = rs_ % 3;                                         \
    const unsigned short* ga = xb + ((size_t)(h + r_) * 130 + s_) * 128 + kc_ * 32; \
    const unsigned short* gb = wtb + rs_ * 16384 + kc_ * 32;                      \
    unsigned short* la = lsh + (nxt) * 8192;                                      \
    gll16(ga + a0off,        la + tid * 8);                                       \
    gll16(ga + a0off + 8192, la + 2048 + tid * 8);                                \
    gll16(gb + a0off,        la + 4096 + tid * 8);                                \
    gll16(gb + a0off + 8192, la + 6144 + tid * 8);                                \
}

    STAGE(0, 0);
    __syncthreads();  // drains vmcnt (compiler barrier semantics)

    #pragma unroll
    for (int st = 0; st < 36; ++st) {
        const int cur = st & 1;
        if (st < 35) STAGE(st + 1, cur ^ 1);
        const int ce = cur * 8192;
        short8 bv[4];
        #pragma unroll
        for (int ft = 0; ft < 4; ++ft)
            bv[ft] = *(const short8*)(lsh + ce + bb_rd + ft * 512);
        #pragma unroll
        for (int mt = 0; mt < 4; ++mt) {
            const short8 av = *(const short8*)(lsh + ce + ab_rd + mt * 512);
            #pragma unroll
            for (int ft = 0; ft < 4; ++ft)
                acc[mt][ft] = __builtin_amdgcn_mfma_f32_16x16x32_bf16(av, bv[ft], acc[mt][ft], 0, 0, 0);
        }
        __syncthreads();  // one barrier/step: drains staging (vmcnt) + reads (lgkm)
    }
#undef STAGE

    // D: col=lane&15 -> f-within-tile, row=quad*4+reg -> w-within-Mtile.
    float* ob = out + ((size_t)(b * 128 + h) * 128) * 128;
    #pragma unroll
    for (int mt = 0; mt < 4; ++mt) {
        #pragma unroll
        for (int reg = 0; reg < 4; ++reg) {
            const int w = wrb + mt * 16 + quad * 4 + reg;
            #pragma unroll
            for (int ft = 0; ft < 4; ++ft)
                ob[(size_t)w * 128 + fcb + ft * 16 + fl] = acc[mt][ft][reg];
        }
    }
}

// ---------------- R2 fallback (used only if ws too small) ----------------
__global__ void mdconv_fb(const float* __restrict__ x,
                          const unsigned short* __restrict__ wt,
                          float* __restrict__ out) {
    const int lin = blockIdx.x;
    const int b   = lin & 7;
    const int sp  = lin >> 3;
    const int h0  = (sp >> 3) * 8;
    const int w0  = (sp & 7) * 16;
    const int tid = threadIdx.x;
    __shared__ unsigned short xs[180 * 138];
    {
        const float* xb = x + (size_t)b * (128 * 128 * 128);
        for (int id = tid; id < 180 * 16; id += 256) {
            int p  = id >> 4;
            int cg = id & 15;
            int pr = p / 18;
            int pc = p - pr * 18;
            int hh = h0 - 1 + pr;
            int ww = w0 - 1 + pc;
            ushort8 v = {0, 0, 0, 0, 0, 0, 0, 0};
            if ((unsigned)hh < 128u && (unsigned)ww < 128u) {
                const float4* src = (const float4*)(xb + ((size_t)(hh * 128 + ww) * 128 + cg * 8));
                float4 f0 = src[0];
                float4 f1 = src[1];
                v[0] = f2bf(f0.x); v[1] = f2bf(f0.y); v[2] = f2bf(f0.z); v[3] = f2bf(f0.w);
                v[4] = f2bf(f1.x); v[5] = f2bf(f1.y); v[6] = f2bf(f1.z); v[7] = f2bf(f1.w);
            }
            *(ushort8*)(xs + p * 138 + cg * 8) = v;
        }
    }
    __syncthreads();
    const int lane = tid & 63;
    const int wave = tid >> 6;
    const int fl   = lane & 15;
    const int quad = lane >> 4;
    const int kq   = quad * 8;
    f32x4 acc[8][2];
    #pragma unroll
    for (int mt = 0; mt < 8; ++mt)
        #pragma unroll
        for (int j = 0; j < 2; ++j)
            acc[mt][j] = (f32x4){0.f, 0.f, 0.f, 0.f};
    const unsigned short* wtb = wt + (size_t)b * (9 * 128 * 128) + (size_t)wave * 4096 + fl * 128 + kq;
    #pragma unroll
    for (int rs = 0; rs < 9; ++rs) {
        const int r = rs / 3, s = rs % 3;
        #pragma unroll
        for (int kc = 0; kc < 4; ++kc) {
            const int k0 = kc * 32 + kq;
            short8 a[8];
            #pragma unroll
            for (int mt = 0; mt < 8; ++mt)
                a[mt] = *(const short8*)(xs + ((mt + r) * 18 + fl + s) * 138 + k0);
            #pragma unroll
            for (int j = 0; j < 2; ++j) {
                short8 bf = *(const short8*)(wtb + rs * 16384 + j * 2048 + kc * 32);
                #pragma unroll
                for (int mt = 0; mt < 8; ++mt)
                    acc[mt][j] = __builtin_amdgcn_mfma_f32_16x16x32_bf16(a[mt], bf, acc[mt][j], 0, 0, 0);
            }
        }
    }
    float* ob = out + ((size_t)(b * 128 + h0) * 128 + w0) * 128;
    #pragma unroll
    for (int mt = 0; mt < 8; ++mt)
        #pragma unroll
        for (int j = 0; j < 2; ++j) {
            const int f = (wave * 2 + j) * 16 + fl;
            #pragma unroll
            for (int reg = 0; reg < 4; ++reg)
                ob[((size_t)(mt * 128 + quad * 4 + reg)) * 128 + f] = acc[mt][j][reg];
        }
}

extern "C" void kernel_launch(void* const* d_in, const int* in_sizes, int n_in,
                              void* d_out, int out_size, void* d_ws, size_t ws_size,
                              hipStream_t stream) {
    const float* x     = (const float*)d_in[0];
    const float* style = (const float*)d_in[1];
    const float* kern  = (const float*)d_in[2];
    float* out = (float*)d_out;

    const size_t XBF_BYTES = (size_t)8 * 130 * 130 * 128 * 2;  // 34,611,200
    const size_t WT_BYTES  = (size_t)8 * 9 * 128 * 128 * 2;    //  2,359,296
    const size_t NEED      = XBF_BYTES + WT_BYTES + 36864;

    if (ws_size >= NEED) {
        unsigned short* xbf = (unsigned short*)d_ws;
        unsigned short* wt  = (unsigned short*)((char*)d_ws + XBF_BYTES);
        float* partial      = (float*)((char*)d_ws + XBF_BYTES + WT_BYTES);
        prep_sumsq<<<dim3(9, 8), dim3(256), 0, stream>>>(kern, style, partial);
        prep_wt<<<dim3(9, 8), dim3(256), 0, stream>>>(kern, style, partial, wt);
        cvt_x<<<dim3((8 * 130 * 130 * 16 + 255) / 256), dim3(256), 0, stream>>>(x, xbf);
        mdconv6<<<dim3(1024), dim3(256), 0, stream>>>(xbf, wt, out);
    } else {
        unsigned short* wt = (unsigned short*)d_ws;
        float* partial     = (float*)((char*)d_ws + WT_BYTES);
        prep_sumsq<<<dim3(9, 8), dim3(256), 0, stream>>>(kern, style, partial);
        prep_wt<<<dim3(9, 8), dim3(256), 0, stream>>>(kern, style, partial, wt);
        mdconv_fb<<<dim3(1024), dim3(256), 0, stream>>>(x, wt, out);
    }
}